// Round 2
// 524.345 us; speedup vs baseline: 1.1806x; 1.1806x over previous
//
#include <hip/hip_runtime.h>
#include <hip/hip_bf16.h>
#include <stdint.h>

#define BB 4
#define SS 4096
#define DD 256

typedef __attribute__((ext_vector_type(4))) float f32x4;
typedef __attribute__((ext_vector_type(8))) short s16x8;

__device__ __forceinline__ ushort f2bf(float f) {
  __hip_bfloat16 h = __float2bfloat16(f);
  return __builtin_bit_cast(ushort, h);
}

// ---------------- kernel 1: fp32 -> bf16 pack ----------------
__global__ void convert_kernel(const float* __restrict__ X,
                               const float* __restrict__ Wq,
                               const float* __restrict__ Wk,
                               const float* __restrict__ Wv,
                               const float* __restrict__ bq,
                               const float* __restrict__ bk,
                               const float* __restrict__ bv,
                               ushort* __restrict__ Xb,
                               ushort* __restrict__ Wb,
                               float* __restrict__ bias) {
  int tid = blockIdx.x * blockDim.x + threadIdx.x;
  int stride = gridDim.x * blockDim.x;
  const int NX4 = (BB * SS * DD) / 4;
  for (int i = tid; i < NX4; i += stride) {
    float4 v = ((const float4*)X)[i];
    ushort4 o = { f2bf(v.x), f2bf(v.y), f2bf(v.z), f2bf(v.w) };
    ((ushort4*)Xb)[i] = o;
  }
  const int NW4 = (DD * DD) / 4;
  for (int i = tid; i < NW4; i += stride) {
    float4 a = ((const float4*)Wq)[i];
    float4 b = ((const float4*)Wk)[i];
    float4 c = ((const float4*)Wv)[i];
    ushort4 oa = { f2bf(a.x), f2bf(a.y), f2bf(a.z), f2bf(a.w) };
    ushort4 ob = { f2bf(b.x), f2bf(b.y), f2bf(b.z), f2bf(b.w) };
    ushort4 oc = { f2bf(c.x), f2bf(c.y), f2bf(c.z), f2bf(c.w) };
    ((ushort4*)Wb)[i]           = oa;
    ((ushort4*)Wb)[NW4 + i]     = ob;
    ((ushort4*)Wb)[2 * NW4 + i] = oc;
  }
  if (tid < DD) {
    bias[tid]          = bq[tid];
    bias[DD + tid]     = bk[tid];
    bias[2 * DD + tid] = bv[tid];
  }
}

// ---------------- kernel 2: fused QKV projection GEMM ----------------
#define LROW 40  // padded LDS row stride (bf16 elems); 80B = 20 dwords -> 2-way bank alias (free)

__global__ __launch_bounds__(256) void proj_gemm(const ushort* __restrict__ Xb,
                                                 const ushort* __restrict__ Wb,
                                                 const float* __restrict__ bias,
                                                 ushort* __restrict__ Qb,
                                                 ushort* __restrict__ Kb,
                                                 ushort* __restrict__ Vt) {
  __shared__ ushort Al[128 * LROW];
  __shared__ ushort Bl[128 * LROW];
  const int m0 = blockIdx.x * 128;
  const int n0 = blockIdx.y * 128;
  const int t = threadIdx.x;
  const int lane = t & 63;
  const int w = t >> 6;
  const int wr = w & 1, wc = w >> 1;
  const int col = lane & 15;
  const int quad = lane >> 4;

  f32x4 acc[4][4];
#pragma unroll
  for (int i = 0; i < 4; i++)
#pragma unroll
    for (int j = 0; j < 4; j++) acc[i][j] = f32x4{0.f, 0.f, 0.f, 0.f};

  const int ci0 = t, ci1 = 256 + t;
  const int r0 = ci0 >> 2, c0 = ci0 & 3;
  const int r1 = ci1 >> 2, c1 = ci1 & 3;

  s16x8 pa0 = *(const s16x8*)(Xb + (m0 + r0) * DD + c0 * 8);
  s16x8 pa1 = *(const s16x8*)(Xb + (m0 + r1) * DD + c1 * 8);
  s16x8 pb0 = *(const s16x8*)(Wb + (n0 + r0) * DD + c0 * 8);
  s16x8 pb1 = *(const s16x8*)(Wb + (n0 + r1) * DD + c1 * 8);

  for (int kk = 0; kk < DD; kk += 32) {
    __syncthreads();
    *(s16x8*)&Al[r0 * LROW + c0 * 8] = pa0;
    *(s16x8*)&Al[r1 * LROW + c1 * 8] = pa1;
    *(s16x8*)&Bl[r0 * LROW + c0 * 8] = pb0;
    *(s16x8*)&Bl[r1 * LROW + c1 * 8] = pb1;
    __syncthreads();
    const int kn = kk + 32;
    if (kn < DD) {
      pa0 = *(const s16x8*)(Xb + (m0 + r0) * DD + kn + c0 * 8);
      pa1 = *(const s16x8*)(Xb + (m0 + r1) * DD + kn + c1 * 8);
      pb0 = *(const s16x8*)(Wb + (n0 + r0) * DD + kn + c0 * 8);
      pb1 = *(const s16x8*)(Wb + (n0 + r1) * DD + kn + c1 * 8);
    }
    s16x8 af[4], bfr[4];
#pragma unroll
    for (int mi = 0; mi < 4; mi++)
      af[mi] = *(const s16x8*)&Al[(wr * 64 + mi * 16 + col) * LROW + quad * 8];
#pragma unroll
    for (int ni = 0; ni < 4; ni++)
      bfr[ni] = *(const s16x8*)&Bl[(wc * 64 + ni * 16 + col) * LROW + quad * 8];
#pragma unroll
    for (int mi = 0; mi < 4; mi++)
#pragma unroll
      for (int ni = 0; ni < 4; ni++)
        acc[mi][ni] = __builtin_amdgcn_mfma_f32_16x16x32_bf16(af[mi], bfr[ni], acc[mi][ni], 0, 0, 0);
  }

  const int region = n0 >> 8;  // 0=Q, 1=K, 2=V
#pragma unroll
  for (int mi = 0; mi < 4; mi++) {
    const int gm = m0 + wr * 64 + mi * 16 + quad * 4;
#pragma unroll
    for (int ni = 0; ni < 4; ni++) {
      const int gn = n0 + wc * 64 + ni * 16 + col;
      const float bb = bias[gn];
      f32x4 v = acc[mi][ni];
      if (region == 0) {
#pragma unroll
        for (int rg = 0; rg < 4; rg++)
          Qb[(gm + rg) * DD + gn] = f2bf((v[rg] + bb) * 0.015625f);  // exact /64
      } else if (region == 1) {
        const int d = gn - 256;
#pragma unroll
        for (int rg = 0; rg < 4; rg++)
          Kb[(gm + rg) * DD + d] = f2bf(v[rg] + bb);
      } else {
        const int d = gn - 512;
        const int b = gm >> 12;
        const int s = gm & (SS - 1);
        ushort4 o = { f2bf(v[0] + bb), f2bf(v[1] + bb), f2bf(v[2] + bb), f2bf(v[3] + bb) };
        *(ushort4*)&Vt[((size_t)(b << 8) + d) * SS + s] = o;
      }
    }
  }
}

// ---------------- kernel 3: flash attention ----------------
// 512 threads = 4 row-waves x 2 KV-split groups. Group g owns KV tiles
// [g*64, g*64+64) with private K/V LDS buffers; partial (m,l,O) merged
// through LDS at the end (exact online-softmax combine).
#define NKT 32
#define KROW 264  // 528B = 132 dw -> 2-way alias (free)
#define VROW 40   //  80B =  20 dw -> 2-way alias
#define PROW 40

#define KL_U (NKT * KROW)        // 8448 ushorts
#define VL_U (DD * VROW)         // 10240
#define PL_U (16 * PROW)         // 640
#define VOFF (2 * KL_U)          // 16896
#define POFF (VOFF + 2 * VL_U)   // 37376
#define SM_U (POFF + 8 * PL_U)   // 42496 ushorts = 84992 B

// exchange: 4 waves x 64 lanes x 72 floats (m[4], l[4], O[64]) = 73728 B <= 84992 B
#define XSTRIDE 72

__global__ __launch_bounds__(512) void attn_kernel(const ushort* __restrict__ Qb,
                                                   const ushort* __restrict__ Kb,
                                                   const ushort* __restrict__ Vt,
                                                   const int* __restrict__ mask,
                                                   float* __restrict__ out) {
  __shared__ __align__(16) ushort sm[SM_U];

  const int qt = blockIdx.x;  // 0..63
  const int b = blockIdx.y;   // 0..3
  const int t = threadIdx.x;
  const int g = t >> 8;       // KV-split group: 0 or 1
  const int tg = t & 255;     // thread within group
  const int lane = t & 63;
  const int w = tg >> 6;      // row-wave within group: 0..3
  const int w8 = t >> 6;      // global wave: 0..7  (wave i -> SIMD i&3: pairs g0/g1)
  const int col = lane & 15;
  const int quad = lane >> 4;

  ushort* Kl = sm + g * KL_U;
  ushort* Vl = sm + VOFF + g * VL_U;
  ushort* Pw = sm + POFF + w8 * PL_U;

  const int q0 = qt * 64;
  const int qrow = q0 + w * 16;  // wave's first q row (within batch)

  // Q fragments (A-operand), pre-scaled by 1/64
  s16x8 qf[8];
  {
    const ushort* qp = Qb + ((size_t)b * SS + qrow + col) * DD + quad * 8;
#pragma unroll
    for (int dc = 0; dc < 8; dc++) qf[dc] = *(const s16x8*)(qp + dc * 32);
  }

  int kr[4], kc[4], vd[4], vc[4];
#pragma unroll
  for (int i = 0; i < 4; i++) {
    const int ci = i * 256 + tg;
    kr[i] = ci >> 5; kc[i] = ci & 31;  // K tile: 32 rows x 32 chunks(8)
    vd[i] = ci >> 2; vc[i] = ci & 3;   // Vt tile: 256 d-rows x 4 chunks(8)
  }

  const ushort* Kg = Kb + (size_t)b * SS * DD;
  const ushort* Vg = Vt + (size_t)b * DD * SS;
  const int* Mg = mask + ((size_t)b * SS + qrow + quad * 4) * SS;

  f32x4 Oc[16];
#pragma unroll
  for (int i = 0; i < 16; i++) Oc[i] = f32x4{0.f, 0.f, 0.f, 0.f};
  float m_i[4] = {-INFINITY, -INFINITY, -INFINITY, -INFINITY};
  float l_i[4] = {0.f, 0.f, 0.f, 0.f};

  const int NT2 = (SS / NKT) / 2;  // 64 tiles per group
  const int kb0 = g * NT2 * NKT;   // group's first kv position

  // prefetch this group's tile 0 into registers
  s16x8 pk[4], pv[4];
  int pm[2][4];
#pragma unroll
  for (int i = 0; i < 4; i++) {
    pk[i] = *(const s16x8*)(Kg + (size_t)(kb0 + kr[i]) * DD + kc[i] * 8);
    pv[i] = *(const s16x8*)(Vg + (size_t)vd[i] * SS + kb0 + vc[i] * 8);
  }
#pragma unroll
  for (int jt = 0; jt < 2; jt++)
#pragma unroll
    for (int rg = 0; rg < 4; rg++) pm[jt][rg] = Mg[rg * SS + kb0 + jt * 16 + col];

  for (int tt = 0; tt < NT2; tt++) {
    __syncthreads();
#pragma unroll
    for (int i = 0; i < 4; i++) {
      *(s16x8*)&Kl[kr[i] * KROW + kc[i] * 8] = pk[i];
      *(s16x8*)&Vl[vd[i] * VROW + vc[i] * 8] = pv[i];
    }
    __syncthreads();
    int mcur[2][4];
#pragma unroll
    for (int jt = 0; jt < 2; jt++)
#pragma unroll
      for (int rg = 0; rg < 4; rg++) mcur[jt][rg] = pm[jt][rg];
    if (tt + 1 < NT2) {
      const int k0n = kb0 + (tt + 1) * NKT;
#pragma unroll
      for (int i = 0; i < 4; i++) {
        pk[i] = *(const s16x8*)(Kg + ((size_t)k0n + kr[i]) * DD + kc[i] * 8);
        pv[i] = *(const s16x8*)(Vg + (size_t)vd[i] * SS + k0n + vc[i] * 8);
      }
#pragma unroll
      for (int jt = 0; jt < 2; jt++)
#pragma unroll
        for (int rg = 0; rg < 4; rg++) pm[jt][rg] = Mg[rg * SS + k0n + jt * 16 + col];
    }

    // S = Q K^T (pre-scaled): 2 col-tiles x 8 d-chunks
    f32x4 st[2];
    __builtin_amdgcn_s_setprio(1);
#pragma unroll
    for (int jt = 0; jt < 2; jt++) {
      f32x4 s = f32x4{0.f, 0.f, 0.f, 0.f};
#pragma unroll
      for (int dc = 0; dc < 8; dc++) {
        s16x8 kb = *(const s16x8*)&Kl[(jt * 16 + col) * KROW + dc * 32 + quad * 8];
        s = __builtin_amdgcn_mfma_f32_16x16x32_bf16(qf[dc], kb, s, 0, 0, 0);
      }
      st[jt] = s;
    }
    __builtin_amdgcn_s_setprio(0);
    // mask (nonzero -> -1e9, post-scale, matching reference)
#pragma unroll
    for (int jt = 0; jt < 2; jt++)
#pragma unroll
      for (int rg = 0; rg < 4; rg++)
        if (mcur[jt][rg]) st[jt][rg] = -1e9f;

    // online softmax: per q-row (row = quad*4+rg), reduce over 16 col lanes
    float al[4];
#pragma unroll
    for (int rg = 0; rg < 4; rg++) {
      float v = fmaxf(st[0][rg], st[1][rg]);
      v = fmaxf(v, __shfl_xor(v, 1));
      v = fmaxf(v, __shfl_xor(v, 2));
      v = fmaxf(v, __shfl_xor(v, 4));
      v = fmaxf(v, __shfl_xor(v, 8));
      const float mn = fmaxf(m_i[rg], v);
      al[rg] = __expf(m_i[rg] - mn);
      m_i[rg] = mn;
    }
#pragma unroll
    for (int rg = 0; rg < 4; rg++) {
      const float p0 = __expf(st[0][rg] - m_i[rg]);
      const float p1 = __expf(st[1][rg] - m_i[rg]);
      st[0][rg] = p0; st[1][rg] = p1;
      float s2 = p0 + p1;
      s2 += __shfl_xor(s2, 1);
      s2 += __shfl_xor(s2, 2);
      s2 += __shfl_xor(s2, 4);
      s2 += __shfl_xor(s2, 8);
      l_i[rg] = l_i[rg] * al[rg] + s2;
    }
#pragma unroll
    for (int dt = 0; dt < 16; dt++)
#pragma unroll
      for (int rg = 0; rg < 4; rg++) Oc[dt][rg] *= al[rg];

    // P: C-layout -> LDS -> A-layout (per-wave region, same-wave dependency only)
#pragma unroll
    for (int jt = 0; jt < 2; jt++)
#pragma unroll
      for (int rg = 0; rg < 4; rg++)
        Pw[(quad * 4 + rg) * PROW + jt * 16 + col] = f2bf(st[jt][rg]);
    s16x8 pa = *(const s16x8*)&Pw[col * PROW + quad * 8];

    // O += P * V
    __builtin_amdgcn_s_setprio(1);
#pragma unroll
    for (int dt = 0; dt < 16; dt++) {
      s16x8 vb = *(const s16x8*)&Vl[(dt * 16 + col) * VROW + quad * 8];
      Oc[dt] = __builtin_amdgcn_mfma_f32_16x16x32_bf16(pa, vb, Oc[dt], 0, 0, 0);
    }
    __builtin_amdgcn_s_setprio(0);
  }

  // ---- merge the two KV-split partials (exact online-softmax combine) ----
  __syncthreads();  // everyone done with K/V LDS before reuse as exchange
  float* ex = (float*)sm;
  float* slot = ex + (size_t)(w * 64 + lane) * XSTRIDE;  // 72 f32/lane: m[4], l[4], O[64]
  if (g == 1) {
#pragma unroll
    for (int rg = 0; rg < 4; rg++) { slot[rg] = m_i[rg]; slot[4 + rg] = l_i[rg]; }
#pragma unroll
    for (int dt = 0; dt < 16; dt++) *(f32x4*)&slot[8 + dt * 4] = Oc[dt];
  }
  __syncthreads();
  if (g == 0) {
    float a0[4], a1[4], inv[4];
#pragma unroll
    for (int rg = 0; rg < 4; rg++) {
      const float m1 = slot[rg];
      const float l1 = slot[4 + rg];
      const float mm = fmaxf(m_i[rg], m1);
      a0[rg] = __expf(m_i[rg] - mm);
      a1[rg] = __expf(m1 - mm);
      inv[rg] = 1.0f / (l_i[rg] * a0[rg] + l1 * a1[rg]);
    }
    float* op = out + ((size_t)b * SS + qrow + quad * 4) * DD;
#pragma unroll
    for (int dt = 0; dt < 16; dt++) {
      const f32x4 o1 = *(const f32x4*)&slot[8 + dt * 4];
#pragma unroll
      for (int rg = 0; rg < 4; rg++)
        op[rg * DD + dt * 16 + col] = (Oc[dt][rg] * a0[rg] + o1[rg] * a1[rg]) * inv[rg];
    }
  }
}

extern "C" void kernel_launch(void* const* d_in, const int* in_sizes, int n_in,
                              void* d_out, int out_size, void* d_ws, size_t ws_size,
                              hipStream_t stream) {
  const float* X  = (const float*)d_in[0];
  const int* mask = (const int*)d_in[1];
  const float* Wq = (const float*)d_in[2];
  const float* bq = (const float*)d_in[3];
  const float* Wk = (const float*)d_in[4];
  const float* bk = (const float*)d_in[5];
  const float* Wv = (const float*)d_in[6];
  const float* bv = (const float*)d_in[7];
  float* out = (float*)d_out;

  ushort* base = (ushort*)d_ws;
  ushort* Xb = base;
  ushort* Wb = Xb + (size_t)BB * SS * DD;
  ushort* Qb = Wb + (size_t)3 * DD * DD;
  ushort* Kb = Qb + (size_t)BB * SS * DD;
  ushort* Vt = Kb + (size_t)BB * SS * DD;
  float* bias = (float*)(Vt + (size_t)BB * SS * DD);

  convert_kernel<<<1024, 256, 0, stream>>>(X, Wq, Wk, Wv, bq, bk, bv, Xb, Wb, bias);
  proj_gemm<<<dim3(128, 6), 256, 0, stream>>>(Xb, Wb, bias, Qb, Kb, Vt);
  attn_kernel<<<dim3(64, 4), 512, 0, stream>>>(Qb, Kb, Vt, mask, out);
}